// Round 4
// baseline (350.766 us; speedup 1.0000x reference)
//
#include <hip/hip_runtime.h>
#include <math.h>

#define N_NODES 50000
#define N_EDGES 800000
#define ET (N_EDGES + N_NODES)   // 850000 edges incl. self-loops
#define D 256
#define NEG_SLOPE 0.2f
#define SCAN_ITEMS 1024
#define NB_SCAN ((N_NODES + SCAN_ITEMS - 1) / SCAN_ITEMS)   // 49

typedef __attribute__((ext_vector_type(8))) _Float16 half8;     // MFMA A/B frag (8 f16)
typedef __attribute__((ext_vector_type(8))) unsigned short ushort8;
typedef __attribute__((ext_vector_type(4))) unsigned short us4;
typedef __attribute__((ext_vector_type(4))) float f32x4;

__device__ inline unsigned short f2h(float f) {
    union { _Float16 h; unsigned short u; } v; v.h = (_Float16)f; return v.u;
}
__device__ inline float h2f(unsigned short u) {
    union { unsigned short u; _Float16 h; } v; v.u = u; return (float)v.h;
}

// ---------------- edge format probe (int32 vs int64 edge_index) ----------------
__global__ void detect_fmt(const int* __restrict__ eidx, int* __restrict__ flag) {
    int i = blockIdx.x * 256 + threadIdx.x;
    if (i < 1024 && eidx[2 * i + 1] != 0) atomicOr(flag, 1);  // nonzero odd word -> int32
}

__device__ inline int edge_src(const int* eidx, int is32, int e) {
    if (e >= N_EDGES) return e - N_EDGES;
    return is32 ? eidx[e] : eidx[2 * e];
}
__device__ inline int edge_dst(const int* eidx, int is32, int e) {
    if (e >= N_EDGES) return e - N_EDGES;
    return is32 ? eidx[N_EDGES + e] : eidx[2 * (N_EDGES + e)];
}

// ---------------- CSR build ----------------
__global__ void count_deg(const int* __restrict__ eidx, const int* __restrict__ flag,
                          int* __restrict__ deg) {
    int e = blockIdx.x * 256 + threadIdx.x;
    if (e >= ET) return;
    int is32 = *flag;
    atomicAdd(&deg[edge_dst(eidx, is32, e)], 1);
}

__global__ __launch_bounds__(256) void scan_block_sums(const int* __restrict__ deg,
                                                       int* __restrict__ bsum) {
    __shared__ int wsums[4];
    int base = blockIdx.x * SCAN_ITEMS + threadIdx.x * 4;
    int s = 0;
    #pragma unroll
    for (int k = 0; k < 4; ++k) { int i = base + k; if (i < N_NODES) s += deg[i]; }
    for (int d = 1; d < 64; d <<= 1) s += __shfl_xor(s, d, 64);
    int lane = threadIdx.x & 63, wid = threadIdx.x >> 6;
    if (lane == 0) wsums[wid] = s;
    __syncthreads();
    if (threadIdx.x == 0) bsum[blockIdx.x] = wsums[0] + wsums[1] + wsums[2] + wsums[3];
}

__global__ void scan_carry(const int* __restrict__ bsum, int* __restrict__ carry,
                           int* __restrict__ off) {
    if (threadIdx.x == 0) {
        int run = 0;
        for (int b = 0; b < NB_SCAN; ++b) { carry[b] = run; run += bsum[b]; }
        off[N_NODES] = ET;
    }
}

__global__ __launch_bounds__(256) void scan_write(const int* __restrict__ deg,
                                                  const int* __restrict__ carry,
                                                  int* __restrict__ off,
                                                  int* __restrict__ cur) {
    __shared__ int wsums[4];
    int base = blockIdx.x * SCAN_ITEMS + threadIdx.x * 4;
    int v[4]; int s = 0;
    #pragma unroll
    for (int k = 0; k < 4; ++k) { int i = base + k; v[k] = (i < N_NODES) ? deg[i] : 0; s += v[k]; }
    int inc = s;
    int lane = threadIdx.x & 63, wid = threadIdx.x >> 6;
    for (int d = 1; d < 64; d <<= 1) { int u = __shfl_up(inc, d, 64); if (lane >= d) inc += u; }
    if (lane == 63) wsums[wid] = inc;
    __syncthreads();
    int woff = 0;
    for (int w = 0; w < wid; ++w) woff += wsums[w];
    int excl = woff + inc - s + carry[blockIdx.x];
    #pragma unroll
    for (int k = 0; k < 4; ++k) {
        int i = base + k;
        if (i < N_NODES) { off[i] = excl; cur[i] = excl; excl += v[k]; }
    }
}

__global__ void scatter_edges(const int* __restrict__ eidx, const int* __restrict__ flag,
                              int* __restrict__ cur, int* __restrict__ srcs) {
    int e = blockIdx.x * 256 + threadIdx.x;
    if (e >= ET) return;
    int is32 = *flag;
    int src = edge_src(eidx, is32, e);
    int dst = edge_dst(eidx, is32, e);
    int pos = atomicAdd(&cur[dst], 1);
    srcs[pos] = src;
}

// ---------------- conversions ----------------
__global__ __launch_bounds__(256) void conv_f32_f16(const float* __restrict__ in,
                                                    unsigned short* __restrict__ outh,
                                                    int n4) {
    int i = blockIdx.x * 256 + threadIdx.x;
    if (i >= n4) return;
    float4 v = *(const float4*)&in[(size_t)i * 4];
    us4 o; o.x = f2h(v.x); o.y = f2h(v.y); o.z = f2h(v.z); o.w = f2h(v.w);
    *(us4*)&outh[(size_t)i * 4] = o;
}

// W[K][256] -> Wt[256][K] f16
__global__ void conv_w_t(const float* __restrict__ W, unsigned short* __restrict__ Wt, int K) {
    int k = blockIdx.x, n = threadIdx.x;
    Wt[(size_t)n * K + k] = f2h(W[(size_t)k * D + n]);
}

// ---------------- f16 MFMA GEMM: C[M x 256] = A[M x K] * Bt^T, C stored f16 ----------------
__global__ __launch_bounds__(256) void gemm_f16(const unsigned short* __restrict__ A,
                                                const unsigned short* __restrict__ Bt,
                                                unsigned short* __restrict__ C, int M, int K) {
    __shared__ __align__(16) unsigned short As[128][40];  // [row][k], pad to 40
    __shared__ __align__(16) unsigned short Bs[64][40];   // [n][k]
    int t = threadIdx.x, lane = t & 63, wid = t >> 6;
    int wm = wid >> 1, wn = wid & 1;                      // 2x2 waves, wave tile 64x32
    int row0 = blockIdx.y * 128, col0 = blockIdx.x * 64;
    f32x4 acc[4][2] = {};
    int ar = t >> 1, ap = t & 1;                          // A: 2 thr/row, 32B each
    int bn = t >> 2, bp = t & 3;                          // B: 4 thr/row, 16B each
    for (int k0 = 0; k0 < K; k0 += 32) {
        ushort8 a0 = {0,0,0,0,0,0,0,0}, a1 = {0,0,0,0,0,0,0,0};
        if (row0 + ar < M) {
            const ushort8* p = (const ushort8*)&A[(size_t)(row0 + ar) * K + k0 + ap * 16];
            a0 = p[0]; a1 = p[1];
        }
        *(ushort8*)&As[ar][ap * 16]     = a0;
        *(ushort8*)&As[ar][ap * 16 + 8] = a1;
        *(ushort8*)&Bs[bn][bp * 8] = *(const ushort8*)&Bt[(size_t)(col0 + bn) * K + k0 + bp * 8];
        __syncthreads();
        half8 af[4], bg[2];
        #pragma unroll
        for (int mi = 0; mi < 4; ++mi)
            af[mi] = *(const half8*)&As[wm * 64 + mi * 16 + (lane & 15)][(lane >> 4) * 8];
        #pragma unroll
        for (int ni = 0; ni < 2; ++ni)
            bg[ni] = *(const half8*)&Bs[wn * 32 + ni * 16 + (lane & 15)][(lane >> 4) * 8];
        #pragma unroll
        for (int mi = 0; mi < 4; ++mi)
            #pragma unroll
            for (int ni = 0; ni < 2; ++ni)
                acc[mi][ni] = __builtin_amdgcn_mfma_f32_16x16x32_f16(af[mi], bg[ni], acc[mi][ni], 0, 0, 0);
        __syncthreads();
    }
    #pragma unroll
    for (int mi = 0; mi < 4; ++mi) {
        int rowb = row0 + wm * 64 + mi * 16 + ((lane >> 4) << 2);
        #pragma unroll
        for (int ni = 0; ni < 2; ++ni) {
            int col = col0 + wn * 32 + ni * 16 + (lane & 15);
            #pragma unroll
            for (int r = 0; r < 4; ++r)
                if (rowb + r < M) C[(size_t)(rowb + r) * D + col] = f2h(acc[mi][ni][r]);
        }
    }
}

// ---------------- attention scores from f16 h ----------------
template <int HEADS>
__global__ __launch_bounds__(256) void attn_scores(const unsigned short* __restrict__ h,
                                                   const float* __restrict__ a_src,
                                                   const float* __restrict__ a_dst,
                                                   float* __restrict__ es,
                                                   float* __restrict__ ed) {
    int node = blockIdx.x * 4 + (threadIdx.x >> 6);
    int lane = threadIdx.x & 63;
    if (node >= N_NODES) return;
    us4 v = *(const us4*)&h[(size_t)node * D + lane * 4];
    float4 as = *(const float4*)&a_src[lane * 4];
    float4 ad = *(const float4*)&a_dst[lane * 4];
    float vx = h2f(v.x), vy = h2f(v.y), vz = h2f(v.z), vw = h2f(v.w);
    float ps = vx * as.x + vy * as.y + vz * as.z + vw * as.w;
    float pd = vx * ad.x + vy * ad.y + vz * ad.z + vw * ad.w;
    const int GS = 64 / HEADS;
    #pragma unroll
    for (int d2 = 1; d2 < GS; d2 <<= 1) {
        ps += __shfl_xor(ps, d2, 64);
        pd += __shfl_xor(pd, d2, 64);
    }
    if ((lane & (GS - 1)) == 0) {
        int hd = lane / GS;
        es[(size_t)node * HEADS + hd] = ps;
        ed[(size_t)node * HEADS + hd] = pd;
    }
}

// ---------------- softmax stats: (edn, m, 1/s) per node x head ----------------
template <int H>
__global__ __launch_bounds__(256) void softmax_stats(const float* __restrict__ es,
                                                     const float* __restrict__ ed,
                                                     const int* __restrict__ off,
                                                     const int* __restrict__ srcs,
                                                     float4* __restrict__ stats) {
    int n = blockIdx.x * 4 + (threadIdx.x >> 6);
    if (n >= N_NODES) return;
    int lane = threadIdx.x & 63;
    int begin = off[n], end = off[n + 1];
    int j  = (H == 8) ? (lane >> 3) : lane;
    int hd = (H == 8) ? (lane & 7) : 0;
    const int JS = (H == 8) ? 8 : 64;
    float edn = ed[(size_t)n * H + hd];
    float m = -1e30f, s = 0.f;
    for (int i = begin + j; i < end; i += JS) {
        float e = es[(size_t)srcs[i] * H + hd] + edn;
        e = e > 0.f ? e : NEG_SLOPE * e;
        float nm = fmaxf(m, e);
        s = s * __expf(m - nm) + __expf(e - nm);
        m = nm;
    }
    #pragma unroll
    for (int mask = (H == 8) ? 8 : 1; mask < 64; mask <<= 1) {
        float om = __shfl_xor(m, mask, 64);
        float os = __shfl_xor(s, mask, 64);
        float nm = fmaxf(m, om);
        s = s * __expf(m - nm) + os * __expf(om - nm);
        m = nm;
    }
    if (j == 0 && ((H == 8) || lane == 0))
        stats[(size_t)n * H + hd] = make_float4(edn, m, 1.f / s, 0.f);
}

// ---------------- gather + inline alpha + bias + elu; 2 edges/wave, 16B/lane ----------------
template <int H, bool OUT_F16>
__global__ __launch_bounds__(256) void gather_agg2(const unsigned short* __restrict__ h,
                                                   const float* __restrict__ es,
                                                   const float4* __restrict__ stats,
                                                   const int* __restrict__ off,
                                                   const int* __restrict__ srcs,
                                                   const float* __restrict__ bias,
                                                   void* __restrict__ outv) {
    int n = blockIdx.x * 4 + (threadIdx.x >> 6);
    if (n >= N_NODES) return;
    int lane = threadIdx.x & 63;
    int half = lane >> 5;                       // which edge of the pair
    int cl   = lane & 31;                       // 8 channels per lane: [cl*8, cl*8+8)
    int head = (H == 8) ? (cl >> 2) : 0;        // 32 ch per head -> 4 lanes per head
    int begin = off[n], end = off[n + 1];
    float4 st = stats[(size_t)n * H + head];
    float edn = st.x, m = st.y, inv_s = st.z;
    float acc[8] = {};
    for (int i = begin; i < end; i += 4) {
        int iA = i + half, iB = i + 2 + half;
        float wA = 0.f, wB = 0.f;
        ushort8 vA = {0,0,0,0,0,0,0,0}, vB = {0,0,0,0,0,0,0,0};
        if (iA < end) {
            int s = srcs[iA];
            float e = es[(size_t)s * H + head] + edn;
            e = e > 0.f ? e : NEG_SLOPE * e;
            wA = __expf(e - m) * inv_s;
            vA = *(const ushort8*)&h[(size_t)s * D + cl * 8];
        }
        if (iB < end) {
            int s = srcs[iB];
            float e = es[(size_t)s * H + head] + edn;
            e = e > 0.f ? e : NEG_SLOPE * e;
            wB = __expf(e - m) * inv_s;
            vB = *(const ushort8*)&h[(size_t)s * D + cl * 8];
        }
        #pragma unroll
        for (int k = 0; k < 8; ++k)
            acc[k] += h2f(vA[k]) * wA + h2f(vB[k]) * wB;
    }
    #pragma unroll
    for (int k = 0; k < 8; ++k) acc[k] += __shfl_xor(acc[k], 32, 64);
    if (half == 0) {
        float b[8];
        *(float4*)&b[0] = *(const float4*)&bias[cl * 8];
        *(float4*)&b[4] = *(const float4*)&bias[cl * 8 + 4];
        float r[8];
        #pragma unroll
        for (int k = 0; k < 8; ++k) {
            float v = acc[k] + b[k];
            r[k] = v > 0.f ? v : __expf(v) - 1.f;   // elu
        }
        if (OUT_F16) {
            ushort8 o;
            #pragma unroll
            for (int k = 0; k < 8; ++k) o[k] = f2h(r[k]);
            *(ushort8*)&((unsigned short*)outv)[(size_t)n * D + cl * 8] = o;
        } else {
            float* op = &((float*)outv)[(size_t)n * D + cl * 8];
            *(float4*)&op[0] = make_float4(r[0], r[1], r[2], r[3]);
            *(float4*)&op[4] = make_float4(r[4], r[5], r[6], r[7]);
        }
    }
}

// ---------------- launch ----------------
extern "C" void kernel_launch(void* const* d_in, const int* in_sizes, int n_in,
                              void* d_out, int out_size, void* d_ws, size_t ws_size,
                              hipStream_t stream) {
    const float* x        = (const float*)d_in[0];
    const int*   eidx     = (const int*)d_in[1];
    const float* W1       = (const float*)d_in[2];
    const float* att_src1 = (const float*)d_in[3];
    const float* att_dst1 = (const float*)d_in[4];
    const float* b1       = (const float*)d_in[5];
    const float* W2       = (const float*)d_in[6];
    const float* att_src2 = (const float*)d_in[7];
    const float* att_dst2 = (const float*)d_in[8];
    const float* b2       = (const float*)d_in[9];
    float* out = (float*)d_out;

    char* ws = (char*)d_ws;
    size_t o = 0;
    auto take = [&](size_t bytes) { char* p = ws + o; o = (o + bytes + 255) & ~(size_t)255; return p; };
    unsigned short* hb    = (unsigned short*)take((size_t)N_NODES * D * 2);   // 25.6 MB
    unsigned short* xb    = (unsigned short*)take((size_t)N_NODES * 128 * 2); // 12.8 MB
    unsigned short* zb    = (unsigned short*)take((size_t)N_NODES * D * 2);   // 25.6 MB
    unsigned short* W1t   = (unsigned short*)take((size_t)D * 128 * 2);
    unsigned short* W2t   = (unsigned short*)take((size_t)D * D * 2);
    float4*         stats = (float4*)take((size_t)N_NODES * 8 * 16);          // 6.4 MB
    float* es1  = (float*)take((size_t)N_NODES * 8 * 4);
    float* ed1  = (float*)take((size_t)N_NODES * 8 * 4);
    float* es2  = (float*)take((size_t)N_NODES * 4);
    float* ed2  = (float*)take((size_t)N_NODES * 4);
    int*   off  = (int*)take((size_t)(N_NODES + 1) * 4);
    int*   cur  = (int*)take((size_t)N_NODES * 4);
    int*   srcs = (int*)take((size_t)ET * 4);
    int*   deg  = (int*)take((size_t)N_NODES * 4);
    int*   bsum = (int*)take(256);
    int*   carry= (int*)take(256);
    int*   flag = (int*)take(256);

    hipMemsetAsync(deg, 0, (size_t)N_NODES * 4, stream);
    hipMemsetAsync(flag, 0, 4, stream);

    const int EB = (ET + 255) / 256;
    detect_fmt<<<4, 256, 0, stream>>>(eidx, flag);
    count_deg<<<EB, 256, 0, stream>>>(eidx, flag, deg);
    scan_block_sums<<<NB_SCAN, 256, 0, stream>>>(deg, bsum);
    scan_carry<<<1, 64, 0, stream>>>(bsum, carry, off);
    scan_write<<<NB_SCAN, 256, 0, stream>>>(deg, carry, off, cur);
    scatter_edges<<<EB, 256, 0, stream>>>(eidx, flag, cur, srcs);

    // f16 conversions
    conv_f32_f16<<<(N_NODES * 128 / 4 + 255) / 256, 256, 0, stream>>>(x, xb, N_NODES * 128 / 4);
    conv_w_t<<<128, 256, 0, stream>>>(W1, W1t, 128);
    conv_w_t<<<256, 256, 0, stream>>>(W2, W2t, 256);

    const int NBLK = (N_NODES + 3) / 4;
    // ---- layer 1 ----
    gemm_f16<<<dim3(4, (N_NODES + 127) / 128), 256, 0, stream>>>(xb, W1t, hb, N_NODES, 128);
    attn_scores<8><<<NBLK, 256, 0, stream>>>(hb, att_src1, att_dst1, es1, ed1);
    softmax_stats<8><<<NBLK, 256, 0, stream>>>(es1, ed1, off, srcs, stats);
    gather_agg2<8, true><<<NBLK, 256, 0, stream>>>(hb, es1, stats, off, srcs, b1, zb);
    // ---- layer 2 ----
    gemm_f16<<<dim3(4, (N_NODES + 127) / 128), 256, 0, stream>>>(zb, W2t, hb, N_NODES, 256);
    attn_scores<1><<<NBLK, 256, 0, stream>>>(hb, att_src2, att_dst2, es2, ed2);
    softmax_stats<1><<<NBLK, 256, 0, stream>>>(es2, ed2, off, srcs, stats);
    gather_agg2<1, false><<<NBLK, 256, 0, stream>>>(hb, es2, stats, off, srcs, b2, out);
}